// Round 1
// baseline (428.914 us; speedup 1.0000x reference)
//
#include <hip/hip_runtime.h>
#include <hip/hip_bf16.h>

#define M_TOT 2048
#define I_DIM 512
#define O_DIM 512
#define G_H   50
#define KP    100
#define K_TOT 51200   /* KP * I_DIM */
#define BM    128
#define BN    128
#define NSPLIT 8
#define STEPS 100     /* k' steps per split (one i-block of 64) */

typedef float  f32x4 __attribute__((ext_vector_type(4)));
typedef short  s16x8 __attribute__((ext_vector_type(8)));

static __device__ __forceinline__ unsigned short f2bf(float f) {
  __hip_bfloat16 h = __float2bfloat16(f);
  return *reinterpret_cast<unsigned short*>(&h);
}

__global__ void fkan_zero(float* __restrict__ out) {
  int idx = blockIdx.x * 256 + threadIdx.x;
  f32x4 z = {0.f, 0.f, 0.f, 0.f};
  *(f32x4*)(out + (size_t)idx * 4) = z;
}

// Bt[o][kp'] bf16, kp' = ib*6400 + k*64 + il  (i = ib*64 + il), from C[k][i][o] f32
__global__ void fkan_prep(const float* __restrict__ C, unsigned short* __restrict__ Bt) {
  const int bx = blockIdx.x;            // 0..799
  const int k  = bx >> 3, ib = bx & 7;
  const int o0 = blockIdx.y * 64;
  const size_t ksrc0 = (size_t)k * 512 + ib * 64;   // source row (kappa)
  const size_t kdst0 = (size_t)ib * 6400 + k * 64;  // dest col  (kappa')
  __shared__ float tile[64][65];
  const int tid = threadIdx.x;
  const int tc = tid & 63, tr4 = tid >> 6;
  for (int r = tr4; r < 64; r += 4)
    tile[r][tc] = C[(ksrc0 + r) * 512 + o0 + tc];
  __syncthreads();
  const int wc = tid & 7;        // k-chunk (8 elems)
  const int wr = tid >> 3;       // o-row 0..31
  for (int rr = wr; rr < 64; rr += 32) {
    unsigned int p0 = (unsigned int)f2bf(tile[wc*8+0][rr]) | ((unsigned int)f2bf(tile[wc*8+1][rr]) << 16);
    unsigned int p1 = (unsigned int)f2bf(tile[wc*8+2][rr]) | ((unsigned int)f2bf(tile[wc*8+3][rr]) << 16);
    unsigned int p2 = (unsigned int)f2bf(tile[wc*8+4][rr]) | ((unsigned int)f2bf(tile[wc*8+5][rr]) << 16);
    unsigned int p3 = (unsigned int)f2bf(tile[wc*8+6][rr]) | ((unsigned int)f2bf(tile[wc*8+7][rr]) << 16);
    uint4 u; u.x = p0; u.y = p1; u.z = p2; u.w = p3;
    *(uint4*)(Bt + (size_t)(o0 + rr) * K_TOT + kdst0 + wc * 8) = u;
  }
}

__global__ __launch_bounds__(256, 2) void fkan_gemm(
    const float* __restrict__ x, const unsigned short* __restrict__ Bt,
    const float* __restrict__ bias, float* __restrict__ out) {
  __shared__ uint4 Bs[1024];   // 16 KB: [128 n][64 k] bf16, chunk-swizzled
  char* Bsb = (char*)Bs;

  const int tid  = threadIdx.x;
  const int lane = tid & 63;
  const int wid  = tid >> 6;          // 0..3
  const int wm   = wid >> 1, wn = wid & 1;
  const int bid  = blockIdx.x;
  const int mt   = bid & 15;
  const int nt   = (bid >> 4) & 3;
  const int sp   = bid >> 6;          // split == i-block

  const int m0 = mt * BM, n0 = nt * BN;
  const size_t kappa0 = (size_t)sp * 6400;

  const int lrow = lane & 15;         // row within 16 (A) / col within 16 (B,D)
  const int lkg  = lane >> 4;         // k-group 0..3
  const int srow = lane >> 3;         // staging: row within 8-row block
  const int schunk = lane & 7;        // staging: 16B chunk

  // ---- x preload: 4 rows x 16 i per lane (fixed for whole kernel) ----
  f32x4 xr[4][2][2];
  #pragma unroll
  for (int mi = 0; mi < 4; ++mi) {
    const float* xp = x + (size_t)(m0 + wm*64 + mi*16 + lrow) * I_DIM + sp*64 + lkg*8;
    #pragma unroll
    for (int ks = 0; ks < 2; ++ks) {
      xr[mi][ks][0] = *(const f32x4*)(xp + ks*32);
      xr[mi][ks][1] = *(const f32x4*)(xp + ks*32 + 4);
    }
  }

  f32x4 acc[4][4];
  #pragma unroll
  for (int mi = 0; mi < 4; ++mi)
    #pragma unroll
    for (int ni = 0; ni < 4; ++ni)
      acc[mi][ni] = (f32x4){0.f, 0.f, 0.f, 0.f};

  #pragma unroll 1
  for (int s = 0; s < STEPS; ++s) {
    const float crev  = 0.5f * (float)((s < G_H) ? (s + 1) : (s - 49));
    const float shift = (s < G_H) ? 0.0f : 0.25f;  // cos(t) = sin(t + quarter rev)

    // issue B-tile loads (reg staging)
    uint4 breg[4];
    #pragma unroll
    for (int q = 0; q < 4; ++q) {
      const int rn = (wid*4 + q)*8 + srow;
      breg[q] = *(const uint4*)(Bt + (size_t)(n0 + rn) * K_TOT + kappa0 + (size_t)s*64 + schunk*8);
    }

    // A-gen: 64 features per lane (overlaps B-load latency)
    s16x8 af[4][2];
    #pragma unroll
    for (int mi = 0; mi < 4; ++mi) {
      #pragma unroll
      for (int ks = 0; ks < 2; ++ks) {
        s16x8 a;
        #pragma unroll
        for (int h = 0; h < 2; ++h) {
          #pragma unroll
          for (int j = 0; j < 4; ++j) {
            float r = __builtin_fmaf(xr[mi][ks][h][j], crev, shift);
            asm("v_fract_f32 %0, %1" : "=v"(r) : "v"(r));
            float sv;
            asm("v_sin_f32 %0, %1" : "=v"(sv) : "v"(r));
            a[h*4 + j] = (short)f2bf(sv);
          }
        }
        af[mi][ks] = a;
      }
    }

    __syncthreads();   // previous iter's ds_reads complete
    #pragma unroll
    for (int q = 0; q < 4; ++q) {
      const int rn = (wid*4 + q)*8 + srow;
      *(uint4*)(Bsb + rn*128 + ((schunk ^ srow) << 4)) = breg[q];
    }
    __syncthreads();   // B tile ready

    #pragma unroll
    for (int ks = 0; ks < 2; ++ks) {
      s16x8 bfr[4];
      #pragma unroll
      for (int ni = 0; ni < 4; ++ni) {
        const int nl = wn*64 + ni*16 + lrow;
        const int kc = ks*4 + lkg;
        bfr[ni] = *(const s16x8*)(Bsb + nl*128 + ((kc ^ (nl & 7)) << 4));
      }
      #pragma unroll
      for (int mi = 0; mi < 4; ++mi)
        #pragma unroll
        for (int ni = 0; ni < 4; ++ni)
          acc[mi][ni] = __builtin_amdgcn_mfma_f32_16x16x32_bf16(af[mi][ks], bfr[ni], acc[mi][ni], 0, 0, 0);
    }
  }

  // ---- epilogue: atomic accumulate (bias from split 0 only) ----
  #pragma unroll
  for (int ni = 0; ni < 4; ++ni) {
    const int col = n0 + wn*64 + ni*16 + lrow;
    const float bv = (sp == 0) ? bias[col] : 0.0f;
    #pragma unroll
    for (int mi = 0; mi < 4; ++mi) {
      const int row = m0 + wm*64 + mi*16 + lkg*4;
      #pragma unroll
      for (int j = 0; j < 4; ++j)
        atomicAdd(out + (size_t)(row + j) * O_DIM + col, acc[mi][ni][j] + bv);
    }
  }
}

extern "C" void kernel_launch(void* const* d_in, const int* in_sizes, int n_in,
                              void* d_out, int out_size, void* d_ws, size_t ws_size,
                              hipStream_t stream) {
  const float* x    = (const float*)d_in[0];
  const float* C    = (const float*)d_in[1];
  const float* bias = (const float*)d_in[2];
  float* out = (float*)d_out;
  unsigned short* Bt = (unsigned short*)d_ws;   // 512 x 51200 bf16 = 52.4 MB

  fkan_zero<<<dim3(1024), dim3(256), 0, stream>>>(out);
  fkan_prep<<<dim3(800, 8), dim3(256), 0, stream>>>(C, Bt);
  fkan_gemm<<<dim3(512), dim3(256), 0, stream>>>(x, Bt, bias, out);
}

// Round 2
// 346.228 us; speedup vs baseline: 1.2388x; 1.2388x over previous
//
#include <hip/hip_runtime.h>
#include <hip/hip_bf16.h>

#define NS 100          /* harmonic-phase steps: s=2(k-1)+p, p=0 sin, p=1 cos */
#define TILE_BYTES 8192 /* one B step-tile: 128 o x 32 kappa bf16, swizzled  */

typedef float f32x4 __attribute__((ext_vector_type(4)));
typedef short s16x8 __attribute__((ext_vector_type(8)));
typedef unsigned int u32x4 __attribute__((ext_vector_type(4)));

// round-half-up f32->bf16 pair pack (2 int ops/value; inputs are finite)
static __device__ __forceinline__ unsigned int bfpack(float a, float b) {
  unsigned int ua = __builtin_bit_cast(unsigned int, a);
  unsigned int ub = __builtin_bit_cast(unsigned int, b);
  return ((ua + 0x8000u) >> 16) | ((ub + 0x8000u) & 0xFFFF0000u);
}

__global__ void fkan_zero(float* __restrict__ out) {
  int idx = blockIdx.x * 256 + threadIdx.x;
  f32x4 z = {0.f, 0.f, 0.f, 0.f};
  *(f32x4*)(out + (size_t)idx * 4) = z;
}

// Bt layout: [spnt=nt*16+sp][s][8KB tile]; tile byte (o,c) = o*64 + ((c^((o>>1)&3))<<4),
// chunk = 8 bf16 of C[f(s)][i=sp*32+c*8+j][nt*128+o], j at byte 2j.
__global__ void fkan_prep(const float* __restrict__ C, unsigned short* __restrict__ Bt) {
  __shared__ float ldsF[32][132];
  const int bx = blockIdx.x;           // 0..6399
  const int s = bx % NS;
  const int spnt = bx / NS;            // 0..63
  const int sp = spnt & 15, nt = spnt >> 4;
  const int f = (s >> 1) + 50 * (s & 1);
  const int t = threadIdx.x;

  const float* src = C + ((size_t)f * 512 + sp * 32) * 512 + nt * 128;
  const int col4 = t & 31, row0 = t >> 5;
  #pragma unroll
  for (int rep = 0; rep < 4; ++rep) {
    int r = row0 + rep * 8;
    f32x4 v = *(const f32x4*)(src + (size_t)r * 512 + col4 * 4);
    *(f32x4*)&ldsF[r][col4 * 4] = v;
  }
  __syncthreads();

  char* dst = (char*)Bt + (size_t)(spnt * NS + s) * TILE_BYTES;
  const int o = t & 127;
  const int c0 = t >> 7;               // 0..1
  #pragma unroll
  for (int q = 0; q < 2; ++q) {
    int c = c0 + 2 * q;
    u32x4 p;
    p[0] = bfpack(ldsF[c*8+0][o], ldsF[c*8+1][o]);
    p[1] = bfpack(ldsF[c*8+2][o], ldsF[c*8+3][o]);
    p[2] = bfpack(ldsF[c*8+4][o], ldsF[c*8+5][o]);
    p[3] = bfpack(ldsF[c*8+6][o], ldsF[c*8+7][o]);
    *(u32x4*)(dst + o * 64 + ((c ^ ((o >> 1) & 3)) << 4)) = p;
  }
}

__global__ __launch_bounds__(256, 2) void fkan_gemm(
    const float* __restrict__ x, const unsigned short* __restrict__ Bt,
    const float* __restrict__ bias, float* __restrict__ out) {
  __shared__ __attribute__((aligned(16))) char Bs[2][TILE_BYTES];

  const int tid  = threadIdx.x;
  const int lane = tid & 63;
  const int wid  = tid >> 6;
  const int wm   = wid >> 1, wn = wid & 1;
  const int bid  = blockIdx.x;
  const int mt   = bid & 15;
  const int nt   = (bid >> 4) & 3;
  const int sp   = bid >> 6;           // 0..15 (i-block of 32)
  const int m0 = mt * 128, n0 = nt * 128;
  const int lrow = lane & 15, lkg = lane >> 4;
  const int swz  = (lrow >> 1) & 3;

  // ---- recurrence state: sin/cos(k*pi*x) for 32 x-values per lane ----
  float sk[4][8], ck[4][8], s1[4][8], c1[4][8];
  #pragma unroll
  for (int mi = 0; mi < 4; ++mi) {
    const float* xp = x + (size_t)(m0 + wm*64 + mi*16 + lrow) * 512 + sp*32 + lkg*8;
    f32x4 xa = *(const f32x4*)xp;
    f32x4 xb = *(const f32x4*)(xp + 4);
    #pragma unroll
    for (int j = 0; j < 8; ++j) {
      float xv = (j < 4) ? xa[j] : xb[j - 4];
      float r = xv * 0.5f;                       // revolutions: sin(pi*x)=sin(2pi*(x/2))
      asm("v_fract_f32 %0, %1" : "=v"(r) : "v"(r));
      float sv, cv;
      asm("v_sin_f32 %0, %1" : "=v"(sv) : "v"(r));
      asm("v_cos_f32 %0, %1" : "=v"(cv) : "v"(r));
      s1[mi][j] = sv; c1[mi][j] = cv;
      sk[mi][j] = sv; ck[mi][j] = cv;            // k = 1
    }
  }

  f32x4 acc[4][4];
  #pragma unroll
  for (int mi = 0; mi < 4; ++mi)
    #pragma unroll
    for (int ni = 0; ni < 4; ++ni)
      acc[mi][ni] = (f32x4){0.f, 0.f, 0.f, 0.f};

  const char* gsrc = (const char*)Bt + (size_t)(nt * 16 + sp) * NS * TILE_BYTES + tid * 16;

  auto stage = [&](int buf) {
    __builtin_amdgcn_global_load_lds(
        (const __attribute__((address_space(1))) unsigned int*)(gsrc),
        (__attribute__((address_space(3))) unsigned int*)(&Bs[buf][tid * 16]), 16, 0, 0);
    __builtin_amdgcn_global_load_lds(
        (const __attribute__((address_space(1))) unsigned int*)(gsrc + 4096),
        (__attribute__((address_space(3))) unsigned int*)(&Bs[buf][4096 + tid * 16]), 16, 0, 0);
    gsrc += TILE_BYTES;
  };

  auto step = [&](int buf, float (&st)[4][8]) {
    s16x8 bfr[4];
    #pragma unroll
    for (int ni = 0; ni < 4; ++ni) {
      int o_loc = wn * 64 + ni * 16 + lrow;
      bfr[ni] = *(const s16x8*)(&Bs[buf][o_loc * 64 + ((lkg ^ swz) << 4)]);
    }
    #pragma unroll
    for (int mi = 0; mi < 4; ++mi) {
      u32x4 pk;
      pk[0] = bfpack(st[mi][0], st[mi][1]);
      pk[1] = bfpack(st[mi][2], st[mi][3]);
      pk[2] = bfpack(st[mi][4], st[mi][5]);
      pk[3] = bfpack(st[mi][6], st[mi][7]);
      s16x8 afr = __builtin_bit_cast(s16x8, pk);
      #pragma unroll
      for (int ni = 0; ni < 4; ++ni)
        acc[mi][ni] = __builtin_amdgcn_mfma_f32_16x16x32_bf16(afr, bfr[ni], acc[mi][ni], 0, 0, 0);
    }
  };

  stage(0);
  __syncthreads();
  int cur = 0;
  #pragma unroll 1
  for (int kh = 0; kh < 50; ++kh) {
    stage(cur ^ 1);                 // s = 2*kh+1
    step(cur, sk);                  // sin_k
    __syncthreads();
    cur ^= 1;
    if (kh < 49) stage(cur ^ 1);    // s = 2*kh+2
    step(cur, ck);                  // cos_k
    #pragma unroll
    for (int mi = 0; mi < 4; ++mi)
      #pragma unroll
      for (int j = 0; j < 8; ++j) {
        float t1 = ck[mi][j] * s1[mi][j];
        float t2 = sk[mi][j] * s1[mi][j];
        sk[mi][j] = __builtin_fmaf(sk[mi][j], c1[mi][j], t1);
        ck[mi][j] = __builtin_fmaf(ck[mi][j], c1[mi][j], -t2);
      }
    __syncthreads();
    cur ^= 1;
  }

  // ---- epilogue: atomic accumulate; bias from split 0 only ----
  #pragma unroll
  for (int ni = 0; ni < 4; ++ni) {
    const int col = n0 + wn * 64 + ni * 16 + lrow;
    const float bv = (sp == 0) ? bias[col] : 0.0f;
    #pragma unroll
    for (int mi = 0; mi < 4; ++mi) {
      const int row = m0 + wm * 64 + mi * 16 + lkg * 4;
      #pragma unroll
      for (int j = 0; j < 4; ++j)
        atomicAdd(out + (size_t)(row + j) * 512 + col, acc[mi][ni][j] + bv);
    }
  }
}

extern "C" void kernel_launch(void* const* d_in, const int* in_sizes, int n_in,
                              void* d_out, int out_size, void* d_ws, size_t ws_size,
                              hipStream_t stream) {
  const float* x    = (const float*)d_in[0];
  const float* C    = (const float*)d_in[1];
  const float* bias = (const float*)d_in[2];
  float* out = (float*)d_out;
  unsigned short* Bt = (unsigned short*)d_ws;   // 64 * 100 * 8KB = 52.4 MB

  fkan_zero<<<dim3(1024), dim3(256), 0, stream>>>(out);
  fkan_prep<<<dim3(6400), dim3(256), 0, stream>>>(C, Bt);
  fkan_gemm<<<dim3(1024), dim3(256), 0, stream>>>(x, Bt, bias, out);
}

// Round 3
// 314.635 us; speedup vs baseline: 1.3632x; 1.1004x over previous
//
#include <hip/hip_runtime.h>
#include <hip/hip_bf16.h>

#define NS 100          /* harmonic-phase steps: s=2(k-1)+p, p=0 sin, p=1 cos */
#define TILE_BYTES 8192 /* one B step-tile: 128 o x 32 kappa bf16, swizzled  */

typedef float f32x4 __attribute__((ext_vector_type(4)));
typedef float f32x2 __attribute__((ext_vector_type(2)));
typedef short s16x8 __attribute__((ext_vector_type(8)));
typedef unsigned int u32x4 __attribute__((ext_vector_type(4)));

static __device__ __forceinline__ unsigned int cvtpk(float a, float b) {
  unsigned int r;
  asm("v_cvt_pk_bf16_f32 %0, %1, %2" : "=v"(r) : "v"(a), "v"(b));
  return r;
}

__global__ void fkan_zero(float* __restrict__ out) {
  int idx = blockIdx.x * 256 + threadIdx.x;
  f32x4 z = {0.f, 0.f, 0.f, 0.f};
  *(f32x4*)(out + (size_t)idx * 4) = z;
}

// Bt layout: [spnt=nt*16+sp][s][8KB tile]; tile byte (o,c) = o*64 + ((c^((o>>1)&3))<<4),
// chunk = 8 bf16 of C[f(s)][i=sp*32+c*8+j][nt*128+o], j at byte 2j.
__global__ void fkan_prep(const float* __restrict__ C, unsigned short* __restrict__ Bt) {
  __shared__ float ldsF[32][136];
  const int bx = blockIdx.x;           // 0..6399
  const int s = bx % NS;
  const int spnt = bx / NS;            // 0..63
  const int sp = spnt & 15, nt = spnt >> 4;
  const int f = (s >> 1) + 50 * (s & 1);
  const int t = threadIdx.x;

  const float* src = C + ((size_t)f * 512 + sp * 32) * 512 + nt * 128;
  const int col4 = t & 31, row0 = t >> 5;
  #pragma unroll
  for (int rep = 0; rep < 4; ++rep) {
    int r = row0 + rep * 8;
    f32x4 v = *(const f32x4*)(src + (size_t)r * 512 + col4 * 4);
    *(f32x4*)&ldsF[r][col4 * 4] = v;
  }
  __syncthreads();

  // coalesced stores: lane h writes address-chunk h (16B), data chunk cd
  char* dst = (char*)Bt + (size_t)(spnt * NS + s) * TILE_BYTES;
  #pragma unroll
  for (int q = 0; q < 2; ++q) {
    const int h = t + q * 256;         // 0..511
    const int o = h >> 2;
    const int ca = h & 3;
    const int cd = ca ^ ((o >> 1) & 3);
    u32x4 p;
    p[0] = cvtpk(ldsF[cd*8+0][o], ldsF[cd*8+1][o]);
    p[1] = cvtpk(ldsF[cd*8+2][o], ldsF[cd*8+3][o]);
    p[2] = cvtpk(ldsF[cd*8+4][o], ldsF[cd*8+5][o]);
    p[3] = cvtpk(ldsF[cd*8+6][o], ldsF[cd*8+7][o]);
    *(u32x4*)(dst + h * 16) = p;
  }
}

__global__ __launch_bounds__(256, 2) void fkan_gemm(
    const float* __restrict__ x, const unsigned short* __restrict__ Bt,
    const float* __restrict__ bias, float* __restrict__ out) {
  __shared__ __attribute__((aligned(16))) char Bs[4][TILE_BYTES];  // 32 KB, 4-deep

  const int tid  = threadIdx.x;
  const int lane = tid & 63;
  const int wid  = tid >> 6;
  const int wm   = wid >> 1, wn = wid & 1;
  // XCD-aware swizzle: all 16 mt-sharers of one (nt,sp) B-stream on one XCD
  const int d    = blockIdx.x;
  const int bid  = (d & 7) * 128 + (d >> 3);
  const int mt   = bid & 15;
  const int nt   = (bid >> 4) & 3;
  const int sp   = bid >> 6;           // 0..15 (i-block of 32)
  const int m0 = mt * 128, n0 = nt * 128;
  const int lrow = lane & 15, lkg = lane >> 4;
  const int swz  = (lrow >> 1) & 3;

  // ---- recurrence state: sin/cos(k*pi*x), 32 x per lane, f32x2-packed ----
  f32x2 sk[4][4], ck[4][4], s1[4][4], c1[4][4];
  #pragma unroll
  for (int mi = 0; mi < 4; ++mi) {
    const float* xp = x + (size_t)(m0 + wm*64 + mi*16 + lrow) * 512 + sp*32 + lkg*8;
    f32x4 xa = *(const f32x4*)xp;
    f32x4 xb = *(const f32x4*)(xp + 4);
    #pragma unroll
    for (int p = 0; p < 4; ++p) {
      #pragma unroll
      for (int e = 0; e < 2; ++e) {
        int j = p * 2 + e;
        float xv = (j < 4) ? xa[j] : xb[j - 4];
        float r = xv * 0.5f;                       // revs: sin(pi x)=sin(2pi (x/2))
        asm("v_fract_f32 %0, %1" : "=v"(r) : "v"(r));
        float sv, cv;
        asm("v_sin_f32 %0, %1" : "=v"(sv) : "v"(r));
        asm("v_cos_f32 %0, %1" : "=v"(cv) : "v"(r));
        s1[mi][p][e] = sv; c1[mi][p][e] = cv;
        sk[mi][p][e] = sv; ck[mi][p][e] = cv;      // k = 1
      }
    }
  }

  f32x4 acc[4][4];
  #pragma unroll
  for (int mi = 0; mi < 4; ++mi)
    #pragma unroll
    for (int ni = 0; ni < 4; ++ni)
      acc[mi][ni] = (f32x4){0.f, 0.f, 0.f, 0.f};

  const char* gsrc = (const char*)Bt + (size_t)(nt * 16 + sp) * NS * TILE_BYTES + tid * 16;

  auto stage = [&](int buf, int s) {
    const char* p = gsrc + (size_t)s * TILE_BYTES;
    __builtin_amdgcn_global_load_lds(
        (const __attribute__((address_space(1))) unsigned int*)(p),
        (__attribute__((address_space(3))) unsigned int*)(&Bs[buf][tid * 16]), 16, 0, 0);
    __builtin_amdgcn_global_load_lds(
        (const __attribute__((address_space(1))) unsigned int*)(p + 4096),
        (__attribute__((address_space(3))) unsigned int*)(&Bs[buf][4096 + tid * 16]), 16, 0, 0);
  };

  auto iter = [&](int s, f32x2 (&st)[4][4]) {
    // pack A fragments (register-only; free to schedule around the wait)
    s16x8 af[4];
    #pragma unroll
    for (int mi = 0; mi < 4; ++mi) {
      u32x4 pk;
      pk[0] = cvtpk(st[mi][0][0], st[mi][0][1]);
      pk[1] = cvtpk(st[mi][1][0], st[mi][1][1]);
      pk[2] = cvtpk(st[mi][2][0], st[mi][2][1]);
      pk[3] = cvtpk(st[mi][3][0], st[mi][3][1]);
      af[mi] = __builtin_bit_cast(s16x8, pk);
    }
    // counted wait: tile s's 2 loads are the oldest of 4 outstanding
    if (s < NS - 2) asm volatile("s_waitcnt vmcnt(2)" ::: "memory");
    else            asm volatile("s_waitcnt vmcnt(0)" ::: "memory");
    __builtin_amdgcn_s_barrier();
    if (s < NS - 2) stage((s + 2) & 3, s + 2);   // refill; never drained below 2
    const char* base = &Bs[s & 3][0];
    s16x8 bfr[4];
    #pragma unroll
    for (int ni = 0; ni < 4; ++ni) {
      int o_loc = wn * 64 + ni * 16 + lrow;
      bfr[ni] = *(const s16x8*)(base + o_loc * 64 + ((lkg ^ swz) << 4));
    }
    __builtin_amdgcn_s_setprio(1);
    #pragma unroll
    for (int mi = 0; mi < 4; ++mi)
      #pragma unroll
      for (int ni = 0; ni < 4; ++ni)
        acc[mi][ni] = __builtin_amdgcn_mfma_f32_16x16x32_bf16(af[mi], bfr[ni], acc[mi][ni], 0, 0, 0);
    __builtin_amdgcn_s_setprio(0);
  };

  stage(0, 0);
  stage(1, 1);
  #pragma unroll 1
  for (int kh = 0; kh < 50; ++kh) {
    iter(2 * kh, sk);        // sin_k tile
    iter(2 * kh + 1, ck);    // cos_k tile
    #pragma unroll
    for (int mi = 0; mi < 4; ++mi)
      #pragma unroll
      for (int p = 0; p < 4; ++p) {
        f32x2 so = sk[mi][p], co = ck[mi][p];
        sk[mi][p] = so * c1[mi][p] + co * s1[mi][p];
        ck[mi][p] = co * c1[mi][p] - so * s1[mi][p];
      }
  }

  // ---- epilogue: atomic accumulate; bias from split 0 only ----
  #pragma unroll
  for (int ni = 0; ni < 4; ++ni) {
    const int col = n0 + wn * 64 + ni * 16 + lrow;
    const float bv = (sp == 0) ? bias[col] : 0.0f;
    #pragma unroll
    for (int mi = 0; mi < 4; ++mi) {
      const int row = m0 + wm * 64 + mi * 16 + lkg * 4;
      #pragma unroll
      for (int j = 0; j < 4; ++j)
        atomicAdd(out + (size_t)(row + j) * 512 + col, acc[mi][ni][j] + bv);
    }
  }
}

extern "C" void kernel_launch(void* const* d_in, const int* in_sizes, int n_in,
                              void* d_out, int out_size, void* d_ws, size_t ws_size,
                              hipStream_t stream) {
  const float* x    = (const float*)d_in[0];
  const float* C    = (const float*)d_in[1];
  const float* bias = (const float*)d_in[2];
  float* out = (float*)d_out;
  unsigned short* Bt = (unsigned short*)d_ws;   // 64 * 100 * 8KB = 52.4 MB

  fkan_zero<<<dim3(1024), dim3(256), 0, stream>>>(out);
  fkan_prep<<<dim3(6400), dim3(256), 0, stream>>>(C, Bt);
  fkan_gemm<<<dim3(1024), dim3(256), 0, stream>>>(x, Bt, bias, out);
}

// Round 5
// 281.729 us; speedup vs baseline: 1.5224x; 1.1168x over previous
//
#include <hip/hip_runtime.h>
#include <hip/hip_bf16.h>

#define NS 100          /* steps: s=2(k-1)+p, p=0 sin, p=1 cos */
#define TILE_BYTES 8192 /* B step-tile: [c=0..3][o=0..127] 16B chunks (8 kappa) */

typedef float f32x4 __attribute__((ext_vector_type(4)));
typedef float f32x2 __attribute__((ext_vector_type(2)));
typedef short s16x8 __attribute__((ext_vector_type(8)));
typedef unsigned int u32x4 __attribute__((ext_vector_type(4)));

static __device__ __forceinline__ unsigned int cvtpk(float a, float b) {
  unsigned int r;
  asm("v_cvt_pk_bf16_f32 %0, %1, %2" : "=v"(r) : "v"(a), "v"(b));
  return r;
}

// Bt tile (spnt,s): chunk-major [c][o]: byte = c*2048 + o*16, chunk = 8 bf16 of
// C[f(s)][i = sp*32 + c*8 + j][nt*128 + o].  Also zeroes `out` (blocks 0..1023).
__global__ void fkan_prep(const float* __restrict__ C, unsigned short* __restrict__ Bt,
                          float* __restrict__ out) {
  __shared__ float ldsF[32][136];
  const int bx = blockIdx.x;           // 0..6399
  const int s = bx % NS;
  const int spnt = bx / NS;            // 0..63
  const int sp = spnt & 15, nt = spnt >> 4;
  const int f = (s >> 1) + 50 * (s & 1);
  const int t = threadIdx.x;

  if (bx < 1024) {                     // zero out: 2048*512 f32 = 1024 * 4KB
    f32x4 z = {0.f, 0.f, 0.f, 0.f};
    *(f32x4*)(out + (size_t)bx * 1024 + t * 4) = z;
  }

  const float* src = C + ((size_t)f * 512 + sp * 32) * 512 + nt * 128;
  const int col4 = t & 31, row0 = t >> 5;
  #pragma unroll
  for (int rep = 0; rep < 4; ++rep) {
    int r = row0 + rep * 8;
    *(f32x4*)&ldsF[r][col4 * 4] = *(const f32x4*)(src + (size_t)r * 512 + col4 * 4);
  }
  __syncthreads();

  char* dst = (char*)Bt + (size_t)(spnt * NS + s) * TILE_BYTES;
  #pragma unroll
  for (int q = 0; q < 2; ++q) {
    const int h = t + q * 256;         // 0..511 → linear 16B chunks
    const int c = h >> 7, o = h & 127;
    u32x4 p;
    p[0] = cvtpk(ldsF[c*8+0][o], ldsF[c*8+1][o]);
    p[1] = cvtpk(ldsF[c*8+2][o], ldsF[c*8+3][o]);
    p[2] = cvtpk(ldsF[c*8+4][o], ldsF[c*8+5][o]);
    p[3] = cvtpk(ldsF[c*8+6][o], ldsF[c*8+7][o]);
    *(u32x4*)(dst + h * 16) = p;
  }
}

__global__ __launch_bounds__(256, 3) void fkan_gemm(
    const float* __restrict__ x, const unsigned short* __restrict__ Bt,
    const float* __restrict__ bias, float* __restrict__ out) {
  __shared__ __attribute__((aligned(16))) char Bs[6][TILE_BYTES];  // 48KB, depth-3

  const int tid  = threadIdx.x;
  const int lane = tid & 63;
  const int wid  = tid >> 6;           // wave = 32 rows x 128 cols
  const int d    = blockIdx.x;
  const int bid  = (d & 7) * 128 + (d >> 3);   // XCD swizzle
  const int mt   = bid & 15;
  const int nt   = (bid >> 4) & 3;
  const int sp   = bid >> 6;           // i-block of 32
  const int m0 = mt * 128, n0 = nt * 128;
  const int lrow = lane & 15, lkg = lane >> 4;

  // ---- recurrence state: 16 x per lane (2 rows x 8 i), f32x2-packed ----
  f32x2 sk[2][4], ck[2][4], s1[2][4], c1[2][4];
  #pragma unroll
  for (int mi = 0; mi < 2; ++mi) {
    const float* xp = x + (size_t)(m0 + wid*32 + mi*16 + lrow) * 512 + sp*32 + lkg*8;
    f32x4 xa = *(const f32x4*)xp;
    f32x4 xb = *(const f32x4*)(xp + 4);
    #pragma unroll
    for (int p = 0; p < 4; ++p) {
      #pragma unroll
      for (int e = 0; e < 2; ++e) {
        int j = p * 2 + e;
        float xv = (j < 4) ? xa[j] : xb[j - 4];
        float r = xv * 0.5f;                       // revs: sin(pi x)=sin(2pi(x/2))
        asm("v_fract_f32 %0, %1" : "=v"(r) : "v"(r));
        float sv, cv;
        asm("v_sin_f32 %0, %1" : "=v"(sv) : "v"(r));
        asm("v_cos_f32 %0, %1" : "=v"(cv) : "v"(r));
        s1[mi][p][e] = sv; c1[mi][p][e] = cv;
        sk[mi][p][e] = sv; ck[mi][p][e] = cv;      // k = 1
      }
    }
  }

  f32x4 acc[2][8];
  #pragma unroll
  for (int mi = 0; mi < 2; ++mi)
    #pragma unroll
    for (int ni = 0; ni < 8; ++ni)
      acc[mi][ni] = (f32x4){0.f, 0.f, 0.f, 0.f};

  const char* gp = (const char*)Bt + (size_t)(nt * 16 + sp) * NS * TILE_BYTES + tid * 16;
  int cur = 0;

  auto stage = [&](int buf) {   // 2 glds x 16B per thread, linear
    __builtin_amdgcn_global_load_lds(
        (const __attribute__((address_space(1))) unsigned int*)(gp),
        (__attribute__((address_space(3))) unsigned int*)(&Bs[buf][tid * 16]), 16, 0, 0);
    __builtin_amdgcn_global_load_lds(
        (const __attribute__((address_space(1))) unsigned int*)(gp + 4096),
        (__attribute__((address_space(3))) unsigned int*)(&Bs[buf][4096 + tid * 16]), 16, 0, 0);
    gp += TILE_BYTES;
  };

  // wait_sel: 2 -> vmcnt(4), 1 -> vmcnt(2), 0 -> vmcnt(0)
  auto iter = [&](f32x2 (&st)[2][4], bool do_stage, int wait_sel) {
    if (wait_sel == 2)      asm volatile("s_waitcnt vmcnt(4)" ::: "memory");
    else if (wait_sel == 1) asm volatile("s_waitcnt vmcnt(2)" ::: "memory");
    else                    asm volatile("s_waitcnt vmcnt(0)" ::: "memory");
    __builtin_amdgcn_s_barrier();
    if (do_stage) { int b = cur + 3; if (b >= 6) b -= 6; stage(b); }

    s16x8 af[2];
    #pragma unroll
    for (int mi = 0; mi < 2; ++mi) {
      u32x4 pk;
      pk[0] = cvtpk(st[mi][0][0], st[mi][0][1]);
      pk[1] = cvtpk(st[mi][1][0], st[mi][1][1]);
      pk[2] = cvtpk(st[mi][2][0], st[mi][2][1]);
      pk[3] = cvtpk(st[mi][3][0], st[mi][3][1]);
      af[mi] = __builtin_bit_cast(s16x8, pk);
    }
    const char* base = &Bs[cur][0] + lkg * 2048 + lrow * 16;
    #pragma unroll
    for (int h = 0; h < 2; ++h) {      // ni in halves to cap VGPR pressure
      s16x8 bfr[4];
      #pragma unroll
      for (int q = 0; q < 4; ++q)
        bfr[q] = *(const s16x8*)(base + (h * 4 + q) * 256);
      __builtin_amdgcn_s_setprio(1);
      #pragma unroll
      for (int mi = 0; mi < 2; ++mi)
        #pragma unroll
        for (int q = 0; q < 4; ++q)
          acc[mi][h*4+q] = __builtin_amdgcn_mfma_f32_16x16x32_bf16(af[mi], bfr[q], acc[mi][h*4+q], 0, 0, 0);
      __builtin_amdgcn_s_setprio(0);
    }
    cur = (cur + 1 == 6) ? 0 : cur + 1;
  };

  auto recur = [&]() {
    #pragma unroll
    for (int mi = 0; mi < 2; ++mi)
      #pragma unroll
      for (int p = 0; p < 4; ++p) {
        f32x2 so = sk[mi][p], co = ck[mi][p];
        sk[mi][p] = so * c1[mi][p] + co * s1[mi][p];
        ck[mi][p] = co * c1[mi][p] - so * s1[mi][p];
      }
  };

  stage(0); stage(1); stage(2);        // 6 loads outstanding
  #pragma unroll 1
  for (int kh = 0; kh < 48; ++kh) {
    iter(sk, true, 2);                 // s = 2kh
    iter(ck, true, 2);                 // s = 2kh+1
    recur();
  }
  iter(sk, true, 2);                   // s=96 (stages tile 99)
  iter(ck, false, 2);                  // s=97
  recur();
  iter(sk, false, 1);                  // s=98
  iter(ck, false, 0);                  // s=99

  // ---- epilogue: atomic accumulate; bias from split 0 only ----
  #pragma unroll
  for (int ni = 0; ni < 8; ++ni) {
    const int col = n0 + ni * 16 + lrow;
    const float bv = (sp == 0) ? bias[col] : 0.0f;
    #pragma unroll
    for (int mi = 0; mi < 2; ++mi) {
      const int row = m0 + wid * 32 + mi * 16 + lkg * 4;
      #pragma unroll
      for (int j = 0; j < 4; ++j)
        atomicAdd(out + (size_t)(row + j) * 512 + col, acc[mi][ni][j] + bv);
    }
  }
}

extern "C" void kernel_launch(void* const* d_in, const int* in_sizes, int n_in,
                              void* d_out, int out_size, void* d_ws, size_t ws_size,
                              hipStream_t stream) {
  const float* x    = (const float*)d_in[0];
  const float* C    = (const float*)d_in[1];
  const float* bias = (const float*)d_in[2];
  float* out = (float*)d_out;
  unsigned short* Bt = (unsigned short*)d_ws;   // 64 * 100 * 8KB = 52.4 MB

  fkan_prep<<<dim3(6400), dim3(256), 0, stream>>>(C, Bt, out);
  fkan_gemm<<<dim3(1024), dim3(256), 0, stream>>>(x, Bt, bias, out);
}